// Round 1
// baseline (719.267 us; speedup 1.0000x reference)
//
#include <hip/hip_runtime.h>
#include <math.h>

#define EPSB 1e-5f

constexpr int B_ = 4;
constexpr int C_ = 64;
constexpr int H_ = 160;
constexpr int W_ = 160;
constexpr int HW_ = H_ * W_;

// workspace layout (float offsets)
constexpr size_t X_OFF   = 0;                                   // relu(x1+x2+x3+x4): B*C*HW
constexpr size_t Y1_OFF  = X_OFF  + (size_t)B_ * C_ * HW_;      // conv(f1)+bn @80x80
constexpr size_t Y2_OFF  = Y1_OFF + (size_t)B_ * C_ * 80 * 80;  // conv(f2)+bn @40x40
constexpr size_t Y3_OFF  = Y2_OFF + (size_t)B_ * C_ * 40 * 40;  // conv(f3)+bn @20x20
constexpr size_t OM_OFF  = Y3_OFF + (size_t)B_ * C_ * 20 * 20;  // (sy,sx,mask) per tap: B*9*3*HW
constexpr size_t WR0_OFF = OM_OFF + (size_t)B_ * 9 * 3 * HW_;   // w0 reordered ci-major: 64*64
constexpr size_t WT_OFF  = WR0_OFF + 64 * 64;                   // dcn_w reordered [k][c][o]: 9*64*64
constexpr size_t RW_OFF  = WT_OFF + 9 * 64 * 64;                // off_w reordered [(ci,dy,dx)][k]: 576*27
constexpr size_t SB_OFF  = RW_OFF + 576 * 27;                   // 5 BNs x (scale[64], bias[64])
// total = 11,525,952 floats = 46.1 MB

__global__ __launch_bounds__(256) void prep_kernel(
    const float* __restrict__ g0, const float* __restrict__ b0, const float* __restrict__ m0, const float* __restrict__ v0,
    const float* __restrict__ g1, const float* __restrict__ b1, const float* __restrict__ m1, const float* __restrict__ v1,
    const float* __restrict__ g2, const float* __restrict__ b2, const float* __restrict__ m2, const float* __restrict__ v2,
    const float* __restrict__ g3, const float* __restrict__ b3, const float* __restrict__ m3, const float* __restrict__ v3,
    const float* __restrict__ gf, const float* __restrict__ bf, const float* __restrict__ mf, const float* __restrict__ vf,
    const float* __restrict__ w0, const float* __restrict__ dcn_w, const float* __restrict__ off_w,
    float* __restrict__ ws)
{
    int tid = blockIdx.x * 256 + threadIdx.x;
    if (tid < 320) {  // BN scale/bias fold
        int j = tid >> 6, c = tid & 63;
        const float *g, *b, *m, *v;
        switch (j) {
            case 0: g = g0; b = b0; m = m0; v = v0; break;
            case 1: g = g1; b = b1; m = m1; v = v1; break;
            case 2: g = g2; b = b2; m = m2; v = v2; break;
            case 3: g = g3; b = b3; m = m3; v = v3; break;
            default: g = gf; b = bf; m = mf; v = vf; break;
        }
        float sc = g[c] * rsqrtf(v[c] + EPSB);
        ws[SB_OFF + j * 128 + c]      = sc;
        ws[SB_OFF + j * 128 + 64 + c] = b[c] - m[c] * sc;
        return;
    }
    int t = tid - 320;
    if (t < 4096) {  // wr0[ci*64+o] = w0[o*64+ci]
        int ci = t >> 6, o = t & 63;
        ws[WR0_OFF + t] = w0[o * 64 + ci];
        return;
    }
    t -= 4096;
    if (t < 36864) {  // wt[k*4096 + c*64 + o] = dcn_w[(o*64+c)*9 + k]
        int o = t & 63, c = (t >> 6) & 63, k = t >> 12;
        ws[WT_OFF + t] = dcn_w[(o * 64 + c) * 9 + k];
        return;
    }
    t -= 36864;
    if (t < 15552) {  // rw[rest*27 + k] = off_w[k*576 + rest], rest = ci*9+dy*3+dx
        int k = t % 27, rest = t / 27;
        ws[RW_OFF + rest * 27 + k] = off_w[k * 576 + rest];
        return;
    }
}

// thread = one output element (b, o, p); loop over Cin
__global__ __launch_bounds__(256) void conv1x1_bn_kernel(
    const float* __restrict__ f, const float* __restrict__ wmat,
    const float* __restrict__ sb, float* __restrict__ out, int Cin, int hw)
{
    int tid = blockIdx.x * 256 + threadIdx.x;
    int p = tid % hw;
    int o = (tid / hw) & 63;
    int b = tid / (hw * 64);
    const float* fb = f + (size_t)b * Cin * hw + p;
    const float* wr = wmat + o * Cin;
    float acc = 0.f;
#pragma unroll 4
    for (int ci = 0; ci < Cin; ++ci) acc = fmaf(fb[(size_t)ci * hw], wr[ci], acc);
    out[tid] = fmaf(acc, sb[o], sb[64 + o]);
}

// thread = one (b, pixel); all 64 channels: conv1x1(f0)+bn + 3 bilinear upsample adds + relu
__global__ __launch_bounds__(256) void fuse_kernel(const float* __restrict__ f0, float* __restrict__ ws)
{
    int tid = blockIdx.x * 256 + threadIdx.x;
    int p = tid % HW_, b = tid / HW_;
    int h = p / W_, w = p % W_;
    const float* wr0 = ws + WR0_OFF;
    const float* sb  = ws + SB_OFF;  // bn0

    float acc[64];
#pragma unroll
    for (int o = 0; o < 64; o++) acc[o] = 0.f;

    const float* f0b = f0 + (size_t)b * 64 * HW_ + p;
    for (int ci = 0; ci < 64; ++ci) {
        float fv = f0b[(size_t)ci * HW_];
        const float* wrow = wr0 + ci * 64;
#pragma unroll
        for (int o = 0; o < 64; o++) acc[o] = fmaf(fv, wrow[o], acc[o]);
    }
#pragma unroll
    for (int o = 0; o < 64; o++) acc[o] = fmaf(acc[o], sb[o], sb[64 + o]);

    {   // +upsample x2 from 80x80 (align_corners)
        float fy = h * (79.f / 159.f); int i0 = (int)fy; if (i0 > 78) i0 = 78; float ty = fy - i0;
        float fx = w * (79.f / 159.f); int j0 = (int)fx; if (j0 > 78) j0 = 78; float tx = fx - j0;
        float w00 = (1.f - ty) * (1.f - tx), w01 = (1.f - ty) * tx, w10 = ty * (1.f - tx), w11 = ty * tx;
        const float* y = ws + Y1_OFF + (size_t)b * 64 * 6400 + i0 * 80 + j0;
#pragma unroll
        for (int c = 0; c < 64; c++) {
            const float* yc = y + c * 6400;
            acc[c] += yc[0] * w00 + yc[1] * w01 + yc[80] * w10 + yc[81] * w11;
        }
    }
    {   // +upsample x4 from 40x40
        float fy = h * (39.f / 159.f); int i0 = (int)fy; if (i0 > 38) i0 = 38; float ty = fy - i0;
        float fx = w * (39.f / 159.f); int j0 = (int)fx; if (j0 > 38) j0 = 38; float tx = fx - j0;
        float w00 = (1.f - ty) * (1.f - tx), w01 = (1.f - ty) * tx, w10 = ty * (1.f - tx), w11 = ty * tx;
        const float* y = ws + Y2_OFF + (size_t)b * 64 * 1600 + i0 * 40 + j0;
#pragma unroll
        for (int c = 0; c < 64; c++) {
            const float* yc = y + c * 1600;
            acc[c] += yc[0] * w00 + yc[1] * w01 + yc[40] * w10 + yc[41] * w11;
        }
    }
    {   // +upsample x8 from 20x20
        float fy = h * (19.f / 159.f); int i0 = (int)fy; if (i0 > 18) i0 = 18; float ty = fy - i0;
        float fx = w * (19.f / 159.f); int j0 = (int)fx; if (j0 > 18) j0 = 18; float tx = fx - j0;
        float w00 = (1.f - ty) * (1.f - tx), w01 = (1.f - ty) * tx, w10 = ty * (1.f - tx), w11 = ty * tx;
        const float* y = ws + Y3_OFF + (size_t)b * 64 * 400 + i0 * 20 + j0;
#pragma unroll
        for (int c = 0; c < 64; c++) {
            const float* yc = y + c * 400;
            acc[c] += yc[0] * w00 + yc[1] * w01 + yc[20] * w10 + yc[21] * w11;
        }
    }

    float* x = ws + X_OFF + (size_t)b * 64 * HW_ + p;
#pragma unroll
    for (int c = 0; c < 64; c++) x[(size_t)c * HW_] = fmaxf(acc[c], 0.f);
}

// thread = one (b, pixel); 3x3 conv -> 27 outputs; store (sy, sx, mask) per tap
__global__ __launch_bounds__(256) void offconv_kernel(const float* __restrict__ off_b, float* __restrict__ ws)
{
    int tid = blockIdx.x * 256 + threadIdx.x;
    int p = tid % HW_, b = tid / HW_;
    int h = p / W_, w = p % W_;
    const float* x  = ws + X_OFF + (size_t)b * 64 * HW_;
    const float* rw = ws + RW_OFF;

    float acc[27];
#pragma unroll
    for (int k = 0; k < 27; k++) acc[k] = off_b[k];

    for (int ci = 0; ci < 64; ++ci) {
        const float* xc = x + (size_t)ci * HW_;
#pragma unroll
        for (int dy = 0; dy < 3; dy++) {
            int yy = h + dy - 1;
            if (yy < 0 || yy >= H_) continue;
#pragma unroll
            for (int dx = 0; dx < 3; dx++) {
                int xx = w + dx - 1;
                if (xx < 0 || xx >= W_) continue;
                float xv = xc[yy * W_ + xx];
                const float* rr = rw + (ci * 9 + dy * 3 + dx) * 27;
#pragma unroll
                for (int k = 0; k < 27; k++) acc[k] = fmaf(xv, rr[k], acc[k]);
            }
        }
    }

    float* om = ws + OM_OFF + (size_t)b * 27 * HW_ + p;
#pragma unroll
    for (int k = 0; k < 9; k++) {
        float sy = (float)(h + (k / 3) - 1) + acc[2 * k];
        float sx = (float)(w + (k % 3) - 1) + acc[2 * k + 1];
        float mk = 1.f / (1.f + __expf(-acc[18 + k]));
        om[(size_t)(k * 3 + 0) * HW_] = sy;
        om[(size_t)(k * 3 + 1) * HW_] = sx;
        om[(size_t)(k * 3 + 2) * HW_] = mk;
    }
}

// thread = one (b, pixel); modulated deformable 3x3 conv + final BN + relu
__global__ __launch_bounds__(256) void dcn_kernel(const float* __restrict__ ws, float* __restrict__ out)
{
    int tid = blockIdx.x * 256 + threadIdx.x;
    int p = tid % HW_, b = tid / HW_;
    const float* x  = ws + X_OFF + (size_t)b * 64 * HW_;
    const float* wt = ws + WT_OFF;
    const float* om = ws + OM_OFF + (size_t)b * 27 * HW_ + p;
    const float* sb = ws + SB_OFF + 4 * 128;  // final bn

    float acc[64];
#pragma unroll
    for (int o = 0; o < 64; o++) acc[o] = 0.f;

    for (int k = 0; k < 9; k++) {
        float sy = om[(size_t)(k * 3 + 0) * HW_];
        float sx = om[(size_t)(k * 3 + 1) * HW_];
        float mk = om[(size_t)(k * 3 + 2) * HW_];
        float y0f = floorf(sy), x0f = floorf(sx);
        int y0 = (int)y0f, x0 = (int)x0f;
        float ty = sy - y0f, tx = sx - x0f;

        int   idx[4];
        float wv[4];
#pragma unroll
        for (int cr = 0; cr < 4; cr++) {
            int dy = cr >> 1, dx = cr & 1;
            int yy = y0 + dy, xx = x0 + dx;
            float wy = dy ? ty : 1.f - ty;
            float wx = dx ? tx : 1.f - tx;
            bool valid = (yy >= 0) && (yy < H_) && (xx >= 0) && (xx < W_);
            int yc = min(max(yy, 0), H_ - 1);
            int xc = min(max(xx, 0), W_ - 1);
            idx[cr] = yc * W_ + xc;
            wv[cr]  = valid ? wy * wx * mk : 0.f;
        }

        const float* wk = wt + k * 4096;
        for (int c0 = 0; c0 < 64; c0 += 16) {
            float val[16];
#pragma unroll
            for (int j = 0; j < 16; j++) {
                const float* xc = x + (size_t)(c0 + j) * HW_;
                val[j] = xc[idx[0]] * wv[0] + xc[idx[1]] * wv[1] + xc[idx[2]] * wv[2] + xc[idx[3]] * wv[3];
            }
#pragma unroll
            for (int j = 0; j < 16; j++) {
                const float* wrow = wk + (c0 + j) * 64;
                float vc = val[j];
#pragma unroll
                for (int o = 0; o < 64; o++) acc[o] = fmaf(vc, wrow[o], acc[o]);
            }
        }
    }

    float* outb = out + (size_t)b * 64 * HW_ + p;
#pragma unroll
    for (int o = 0; o < 64; o++)
        outb[(size_t)o * HW_] = fmaxf(fmaf(acc[o], sb[o], sb[64 + o]), 0.f);
}

extern "C" void kernel_launch(void* const* d_in, const int* in_sizes, int n_in,
                              void* d_out, int out_size, void* d_ws, size_t ws_size,
                              hipStream_t stream)
{
    const float* f0 = (const float*)d_in[0];
    const float* f1 = (const float*)d_in[1];
    const float* f2 = (const float*)d_in[2];
    const float* f3 = (const float*)d_in[3];
    const float* w0 = (const float*)d_in[4];
    const float* g0 = (const float*)d_in[5];
    const float* b0 = (const float*)d_in[6];
    const float* m0 = (const float*)d_in[7];
    const float* v0 = (const float*)d_in[8];
    const float* w1 = (const float*)d_in[9];
    const float* g1 = (const float*)d_in[10];
    const float* b1 = (const float*)d_in[11];
    const float* m1 = (const float*)d_in[12];
    const float* v1 = (const float*)d_in[13];
    const float* w2 = (const float*)d_in[14];
    const float* g2 = (const float*)d_in[15];
    const float* b2 = (const float*)d_in[16];
    const float* m2 = (const float*)d_in[17];
    const float* v2 = (const float*)d_in[18];
    const float* w3 = (const float*)d_in[19];
    const float* g3 = (const float*)d_in[20];
    const float* b3 = (const float*)d_in[21];
    const float* m3 = (const float*)d_in[22];
    const float* v3 = (const float*)d_in[23];
    const float* off_w = (const float*)d_in[24];
    const float* off_b = (const float*)d_in[25];
    const float* dcn_w = (const float*)d_in[26];
    const float* gf = (const float*)d_in[27];
    const float* bf = (const float*)d_in[28];
    const float* mf = (const float*)d_in[29];
    const float* vf = (const float*)d_in[30];

    float* ws  = (float*)d_ws;
    float* out = (float*)d_out;

    // prep: 320 + 4096 + 36864 + 15552 = 56,832 threads = 222 * 256
    prep_kernel<<<dim3(222), dim3(256), 0, stream>>>(
        g0, b0, m0, v0, g1, b1, m1, v1, g2, b2, m2, v2, g3, b3, m3, v3,
        gf, bf, mf, vf, w0, dcn_w, off_w, ws);

    // small-scale 1x1 convs + bn
    conv1x1_bn_kernel<<<dim3(6400), dim3(256), 0, stream>>>(f1, w1, ws + SB_OFF + 128, ws + Y1_OFF, 128, 6400);
    conv1x1_bn_kernel<<<dim3(1600), dim3(256), 0, stream>>>(f2, w2, ws + SB_OFF + 256, ws + Y2_OFF, 256, 1600);
    conv1x1_bn_kernel<<<dim3(400),  dim3(256), 0, stream>>>(f3, w3, ws + SB_OFF + 384, ws + Y3_OFF, 512, 400);

    // fuse: conv1x1(f0)+bn + upsample adds + relu -> x
    fuse_kernel<<<dim3(400), dim3(256), 0, stream>>>(f0, ws);

    // offset conv -> (sy, sx, mask)
    offconv_kernel<<<dim3(400), dim3(256), 0, stream>>>(off_b, ws);

    // deformable conv + final bn + relu
    dcn_kernel<<<dim3(400), dim3(256), 0, stream>>>(ws, out);
}